// Round 3
// baseline (916.698 us; speedup 1.0000x reference)
//
#include <hip/hip_runtime.h>
#include <hip/hip_fp16.h>
#include <cstdint>
#include <cstddef>

typedef _Float16 f16;
typedef _Float16 f16x8 __attribute__((ext_vector_type(8)));
typedef _Float16 f16x4 __attribute__((ext_vector_type(4)));
typedef float f32x4 __attribute__((ext_vector_type(4)));

#define NB 64
#define SEQ 512
#define HDIM 1024
#define NHEAD 8
#define HD 128
#define MR (NB * SEQ)      // 32768 rows
#define QK_LD 2048         // q,k packed rows (v goes straight to vT)

// async 16B/lane global->LDS. LDS dest = wave-uniform base + lane*16.
__device__ __forceinline__ void async_copy16(const f16* g, f16* l) {
  __builtin_amdgcn_global_load_lds(
      (__attribute__((address_space(1))) void*)(void*)const_cast<f16*>(g),
      (__attribute__((address_space(3))) void*)l, 16, 0, 0);
}

// ---------------- small prep kernels ----------------

__global__ __launch_bounds__(256) void conv_reduce(
    const float* __restrict__ cw, const float* __restrict__ cb,
    float* __restrict__ out2) {
  int t = threadIdx.x;
  float a = 0.f, b = 0.f;
  for (int i = t; i < HDIM; i += 256) { a += cw[i]; b += cb[i]; }
  for (int m = 32; m >= 1; m >>= 1) { a += __shfl_xor(a, m); b += __shfl_xor(b, m); }
  __shared__ float sa[4], sb[4];
  if ((t & 63) == 0) { sa[t >> 6] = a; sb[t >> 6] = b; }
  __syncthreads();
  if (t == 0) {
    out2[0] = (sa[0] + sa[1] + sa[2] + sa[3]) * (1.f / HDIM);
    out2[1] = (sb[0] + sb[1] + sb[2] + sb[3]) * (1.f / HDIM);
  }
}

// y = x*(1+mean(conv_w)) + mean(conv_b), cast f16. 4 elems/thread.
__global__ __launch_bounds__(256) void prep_x(
    const float* __restrict__ x, const float* __restrict__ cs,
    f16* __restrict__ xh) {
  size_t i = (size_t)blockIdx.x * 256 + threadIdx.x;
  float cw = 1.f + cs[0], cb = cs[1];
  float4 v = ((const float4*)x)[i];
  f16x4 o;
  o[0] = (f16)(v.x * cw + cb);
  o[1] = (f16)(v.y * cw + cb);
  o[2] = (f16)(v.z * cw + cb);
  o[3] = (f16)(v.w * cw + cb);
  ((f16x4*)xh)[i] = o;
}

__global__ __launch_bounds__(256) void concat_bias(
    const float* __restrict__ bq, const float* __restrict__ bk,
    const float* __restrict__ bv, float* __restrict__ dst) {
  int i = blockIdx.x * 256 + threadIdx.x;  // 3072
  if (i < 1024) dst[i] = bq[i];
  else if (i < 2048) dst[i] = bk[i - 1024];
  else dst[i] = bv[i - 2048];
}

// fp32 -> f16 elementwise (no transpose), 4 elems/thread
__global__ __launch_bounds__(256) void cast_f16(
    const float* __restrict__ src, f16* __restrict__ dst) {
  size_t i = (size_t)blockIdx.x * 256 + threadIdx.x;
  float4 v = ((const float4*)src)[i];
  f16x4 o;
  o[0] = (f16)v.x; o[1] = (f16)v.y; o[2] = (f16)v.z; o[3] = (f16)v.w;
  ((f16x4*)dst)[i] = o;
}

// phase1: partial[jc][n] = sum_{j in chunk jc} bo[j]*wp[j][n];  grid (4, 8)
__global__ __launch_bounds__(256) void fuse_bias_p1(
    const float* __restrict__ bo, const float* __restrict__ wp,
    float* __restrict__ partial) {
  int n = blockIdx.x * 256 + threadIdx.x;
  int jc = blockIdx.y;
  float s = 0.f;
#pragma unroll 8
  for (int j = jc * 128; j < jc * 128 + 128; j++) s += bo[j] * wp[(size_t)j * 1024 + n];
  partial[(size_t)jc * 1024 + n] = s;
}

// phase2: bp2[n] = bp[n] + sum_jc partial[jc][n];  grid 4
__global__ __launch_bounds__(256) void fuse_bias_p2(
    const float* __restrict__ partial, const float* __restrict__ bp,
    float* __restrict__ bp2) {
  int n = blockIdx.x * 256 + threadIdx.x;
  float s = bp[n];
#pragma unroll
  for (int jc = 0; jc < 8; jc++) s += partial[(size_t)jc * 1024 + n];
  bp2[n] = s;
}

// W [K,N] fp32 -> WT [N,K] f16 (NT-gemm weight layout)
__global__ __launch_bounds__(256) void transpose_cast(
    const float* __restrict__ src, f16* __restrict__ dst, int K, int N) {
  __shared__ float tile[32][33];
  int tx = threadIdx.x, ty = threadIdx.y;
  int n0 = blockIdx.x * 32, k0 = blockIdx.y * 32;
#pragma unroll
  for (int r = 0; r < 32; r += 8) tile[ty + r][tx] = src[(size_t)(k0 + ty + r) * N + n0 + tx];
  __syncthreads();
#pragma unroll
  for (int r = 0; r < 32; r += 8)
    dst[(size_t)(n0 + ty + r) * K + k0 + tx] = (f16)tile[tx][ty + r];
}

// five 1024x1024 transpose_casts in one launch; z selects (src,dst)
__global__ __launch_bounds__(256) void transpose_cast5(
    const float* s0, const float* s1, const float* s2, const float* s3, const float* s4,
    f16* d0, f16* d1, f16* d2, f16* d3, f16* d4) {
  const float* src; f16* dst;
  switch (blockIdx.z) {
    case 0: src = s0; dst = d0; break;
    case 1: src = s1; dst = d1; break;
    case 2: src = s2; dst = d2; break;
    case 3: src = s3; dst = d3; break;
    default: src = s4; dst = d4; break;
  }
  __shared__ float tile[32][33];
  int tx = threadIdx.x, ty = threadIdx.y;
  int n0 = blockIdx.x * 32, k0 = blockIdx.y * 32;
#pragma unroll
  for (int r = 0; r < 32; r += 8) tile[ty + r][tx] = src[(size_t)(k0 + ty + r) * 1024 + n0 + tx];
  __syncthreads();
#pragma unroll
  for (int r = 0; r < 32; r += 8)
    dst[(size_t)(n0 + ty + r) * 1024 + k0 + tx] = (f16)tile[tx][ty + r];
}

// LayerNorm over H=1024, f16 in (x_regh), f16 out (x_norm)
__global__ __launch_bounds__(256) void ln_kernel(
    const f16* __restrict__ xin, const float* __restrict__ g,
    const float* __restrict__ bta, f16* __restrict__ out) {
  int row = blockIdx.x;
  int t = threadIdx.x;
  f16x4 vh = ((const f16x4*)(xin + (size_t)row * HDIM))[t];
  float vx = (float)vh[0], vy = (float)vh[1], vz = (float)vh[2], vw = (float)vh[3];
  float s = vx + vy + vz + vw;
  float s2 = vx * vx + vy * vy + vz * vz + vw * vw;
  for (int m = 32; m >= 1; m >>= 1) { s += __shfl_xor(s, m); s2 += __shfl_xor(s2, m); }
  __shared__ float sa[4], sb[4];
  if ((t & 63) == 0) { sa[t >> 6] = s; sb[t >> 6] = s2; }
  __syncthreads();
  float S = sa[0] + sa[1] + sa[2] + sa[3];
  float S2 = sb[0] + sb[1] + sb[2] + sb[3];
  float mu = S * (1.f / HDIM);
  float var = S2 * (1.f / HDIM) - mu * mu;
  float inv = rsqrtf(var + 1e-5f);
  float4 gv = ((const float4*)g)[t];
  float4 bv = ((const float4*)bta)[t];
  f16x4 o;
  o[0] = (f16)((vx - mu) * inv * gv.x + bv.x);
  o[1] = (f16)((vy - mu) * inv * gv.y + bv.y);
  o[2] = (f16)((vz - mu) * inv * gv.z + bv.z);
  o[3] = (f16)((vw - mu) * inv * gv.w + bv.w);
  ((f16x4*)(out + (size_t)row * HDIM))[t] = o;
}

// ---------------- main NT GEMM: C[M,N] = A[M,K] @ BT[N,K]^T + bias ----------------
// m97 configuration: 256 threads / 4 waves (2x2 grid, wave tile 64x64), 128x128
// block tile, BK=64.  16 ds_read_b128 per wave per K-tile for 32 wave-MFMA
// (1.5x better LDS economy than the 8-wave 64x32 variant; guide-measured 912 vs
// 858 TF).  Rotated global_load_lds staging (verified 0-conflict chunk rotation:
// chunk (row,phys) holds logical k-chunk (phys - row&7)&7; read phys =
// (s*4+quad+l15&7)&7).  2-barrier K-loop; implicit multi-block TLP (~4 blk/CU).
// EPI: 0 relu->f16 | 1 f16 (also QK: N==QK_LD==2048) | 4 f16 no-bias |
//      5 fp32 = acc+bias+(float)Xres (residual) | 7 V-only -> vT layout
template <int EPI>
__global__ __launch_bounds__(256) void gemm_nt(
    const f16* __restrict__ A, const f16* __restrict__ BT,
    const float* __restrict__ bias, void* __restrict__ Cout, int N, int K,
    const f16* __restrict__ Xres, f16* __restrict__ vTout) {
  __shared__ __align__(16) f16 As[128 * 64];
  __shared__ __align__(16) f16 Bs[128 * 64];
  const int tid = threadIdx.x;
  const int wave = tid >> 6, lane = tid & 63;
  const int l15 = lane & 15, quad = lane >> 4;

  // block swizzle: groups of up to 16 bm, bn inner
  const int gn = N >> 7;
  const int gm = (int)gridDim.x / gn;
  const int pid = blockIdx.x;
  const int npg = 16 * gn;
  const int gid = pid / npg;
  const int rem = pid - gid * npg;
  const int grows = min(16, gm - gid * 16);
  const int bm = gid * 16 + rem % grows;
  const int bn = rem / grows;

  const int wm = wave >> 1, wn = wave & 1;   // 2 x 2 wave grid; wave tile 64x64

  f32x4 z4 = {0.f, 0.f, 0.f, 0.f};
  f32x4 acc[4][4];
#pragma unroll
  for (int i = 0; i < 4; i++)
#pragma unroll
    for (int j = 0; j < 4; j++) acc[i][j] = z4;

  // staging: 4 copies/operand; chunk c = i*256+tid; row = c>>3 = i*32+(tid>>3),
  // phys = tid&7, logical q = (phys - row&7)&7  (i*32 == 0 mod 8 -> same rot)
  const int srow = tid >> 3;
  const int c = ((tid & 7) - (srow & 7)) & 7;
  const f16* Ag = A + (size_t)(bm * 128 + srow) * K + c * 8;
  const f16* Bg = BT + (size_t)(bn * 128 + srow) * K + c * 8;
  const size_t kstep32 = (size_t)32 * K;

  const int r7 = l15 & 7;  // fragment-row rotation

  for (int k0 = 0; k0 < K; k0 += 64) {
#pragma unroll
    for (int i = 0; i < 4; i++) async_copy16(Ag + i * kstep32, As + i * 2048 + tid * 8);
#pragma unroll
    for (int i = 0; i < 4; i++) async_copy16(Bg + i * kstep32, Bs + i * 2048 + tid * 8);
    Ag += 64; Bg += 64;
    __syncthreads();
#pragma unroll
    for (int s = 0; s < 2; s++) {
      const int phys = (s * 4 + quad + r7) & 7;
      f16x8 af[4], bfr[4];
#pragma unroll
      for (int t = 0; t < 4; t++)
        af[t] = *(const f16x8*)&As[(wm * 64 + t * 16 + l15) * 64 + phys * 8];
#pragma unroll
      for (int u = 0; u < 4; u++)
        bfr[u] = *(const f16x8*)&Bs[(wn * 64 + u * 16 + l15) * 64 + phys * 8];
#pragma unroll
      for (int i = 0; i < 4; i++)
#pragma unroll
        for (int j = 0; j < 4; j++)
          acc[i][j] = __builtin_amdgcn_mfma_f32_16x16x32_f16(af[i], bfr[j], acc[i][j], 0, 0, 0);
    }
    __syncthreads();
  }

  float* Cf = (float*)Cout;
  f16* Ch = (f16*)Cout;
#pragma unroll
  for (int i = 0; i < 4; i++) {
    int r0 = bm * 128 + wm * 64 + i * 16 + quad * 4;
#pragma unroll
    for (int j = 0; j < 4; j++) {
      int c0 = bn * 128 + wn * 64 + j * 16;
      int cc = c0 + l15;
      float bv = (EPI == 4) ? 0.f : bias[cc];
      if (EPI == 7) {
        // V-only (N=1024): vT[(b*8+h)*128 + d][m], 4 consecutive m per lane
        int hh = cc >> 7, d = cc & 127;
        int bb = r0 >> 9, ml = r0 & 511;
        f16x4 o;
#pragma unroll
        for (int reg = 0; reg < 4; reg++) o[reg] = (f16)(acc[i][j][reg] + bv);
        *(f16x4*)&vTout[((size_t)(bb * NHEAD + hh) * HD + d) * SEQ + ml] = o;
      } else {
#pragma unroll
        for (int reg = 0; reg < 4; reg++) {
          float v = acc[i][j][reg] + bv;
          if (EPI == 0)      Ch[(size_t)(r0 + reg) * N + cc] = (f16)fmaxf(v, 0.f);
          else if (EPI == 1) Ch[(size_t)(r0 + reg) * N + cc] = (f16)v;
          else if (EPI == 4) Ch[(size_t)(r0 + reg) * N + cc] = (f16)v;
          else if (EPI == 5) {
            size_t idx = (size_t)(r0 + reg) * N + cc;
            Cf[idx] = v + (float)Xres[idx];
          }
        }
      }
    }
  }
}

// ---------------- flash attention with zeroed-diagonal scores ----------------
// grid: 1024 = bh(512) x qc(2).  512 thr / 8 waves; wave owns 32 q-rows (256/block).
// K/VT staged via rotated global_load_lds. Fixed-max softmax (p=exp(s), diag->1).
// Ps wave-private (lgkm wait only). LDS 69 KB -> 2 blocks/CU, 16 waves/CU.
// setprio(1) around MFMA clusters (T5: cross-block wave diversity at 2 blk/CU).
__global__ __launch_bounds__(512) void attn_kernel(
    const f16* __restrict__ qkv, const f16* __restrict__ vT,
    f16* __restrict__ ctx) {
  const int tid = threadIdx.x;
  const int wave = tid >> 6, lane = tid & 63;
  const int l15 = lane & 15, quad = lane >> 4;
  const int bidx = blockIdx.x;
  const int qc = bidx >> 9;            // siblings 512 apart -> same XCD, co-resident
  const int bh = bidx & 511;
  const int h = bh & 7, bb = bh >> 3;

  const f16* Qbase = qkv + (size_t)(bb * SEQ) * QK_LD + h * 128;
  const f16* Kbase = Qbase + 1024;
  const f16* VTbase = vT + (size_t)(bb * NHEAD + h) * HD * SEQ;

  __shared__ __align__(16) f16 Ks[64 * 128];    // rotated chunks
  __shared__ __align__(16) f16 VTs[128 * 64];   // rotated chunks
  __shared__ __align__(16) f16 Ps[8 * 32 * 72]; // per-wave 32 x [72] (64 used)

  const float scale = 0.08838834764831845f;  // 1/sqrt(128)
  const int qrow0 = qc * 256 + wave * 32;
  f16x8 qf[2][4];
#pragma unroll
  for (int tm = 0; tm < 2; tm++)
#pragma unroll
    for (int s = 0; s < 4; s++) {
      qf[tm][s] = *(const f16x8*)(Qbase + (size_t)(qrow0 + tm * 16 + l15) * QK_LD + s * 32 + quad * 8);
#pragma unroll
      for (int e = 0; e < 8; e++) qf[tm][s][e] *= (f16)scale;
    }

  f32x4 z4 = {0.f, 0.f, 0.f, 0.f};
  f32x4 O[2][8];
#pragma unroll
  for (int i = 0; i < 2; i++)
#pragma unroll
    for (int j = 0; j < 8; j++) O[i][j] = z4;
  float lrow[2][4];
#pragma unroll
  for (int i = 0; i < 2; i++)
#pragma unroll
    for (int r = 0; r < 4; r++) lrow[i][r] = 0.f;

  // K staging: row = 32*i + (tid>>4), p = tid&15, c = (p - row&15)&15
  const int kc = ((tid & 15) - ((tid >> 4) & 15)) & 15;
  const f16* Kg = Kbase + (size_t)(tid >> 4) * QK_LD + kc * 8;
  f16* Kl = Ks + tid * 8;
  // VT staging: row = 64*i + (tid>>3), p = tid&7, c = (p - row&7)&7
  const int vc = ((tid & 7) - ((tid >> 3) & 7)) & 7;
  const f16* Vg = VTbase + (size_t)(tid >> 3) * SEQ + vc * 8;
  f16* Vl = VTs + tid * 8;

  f16* Pw = &Ps[wave * 32 * 72];
  const int r7 = l15 & 7;

  for (int kt = 0; kt < 8; kt++) {
    const int krow0 = kt * 64;
#pragma unroll
    for (int i = 0; i < 2; i++)
      async_copy16(Kg + (size_t)(krow0 + 32 * i) * QK_LD, Kl + 4096 * i);
#pragma unroll
    for (int i = 0; i < 2; i++)
      async_copy16(Vg + (size_t)(64 * i) * SEQ + krow0, Vl + 4096 * i);
    __syncthreads();

    // S = Q @ K^T
    f32x4 S[2][4];
#pragma unroll
    for (int i = 0; i < 2; i++)
#pragma unroll
      for (int j = 0; j < 4; j++) S[i][j] = z4;
#pragma unroll
    for (int s = 0; s < 4; s++) {
      f16x8 bfr[4];
#pragma unroll
      for (int tn = 0; tn < 4; tn++) {
        int phys = (s * 4 + quad + l15) & 15;
        bfr[tn] = *(const f16x8*)&Ks[(tn * 16 + l15) * 128 + phys * 8];
      }
      __builtin_amdgcn_s_setprio(1);
#pragma unroll
      for (int tm = 0; tm < 2; tm++)
#pragma unroll
        for (int tn = 0; tn < 4; tn++)
          S[tm][tn] = __builtin_amdgcn_mfma_f32_16x16x32_f16(qf[tm][s], bfr[tn], S[tm][tn], 0, 0, 0);
      __builtin_amdgcn_s_setprio(0);
    }

    // fixed-max softmax (diag -> exp(0)=1)
#pragma unroll
    for (int tm = 0; tm < 2; tm++) {
#pragma unroll
      for (int reg = 0; reg < 4; reg++) {
        int qg = qrow0 + tm * 16 + quad * 4 + reg;
        float rs = 0.f;
#pragma unroll
        for (int tn = 0; tn < 4; tn++) {
          int kg = krow0 + tn * 16 + l15;
          float p = (kg == qg) ? 1.f : __expf(S[tm][tn][reg]);
          S[tm][tn][reg] = p;
          rs += p;
        }
        rs += __shfl_xor(rs, 1); rs += __shfl_xor(rs, 2);
        rs += __shfl_xor(rs, 4); rs += __shfl_xor(rs, 8);
        lrow[tm][reg] += rs;
      }
    }

    // P: C-layout -> LDS (wave-private) -> A-layout
#pragma unroll
    for (int tm = 0; tm < 2; tm++)
#pragma unroll
      for (int reg = 0; reg < 4; reg++)
#pragma unroll
        for (int tn = 0; tn < 4; tn++)
          Pw[(tm * 16 + quad * 4 + reg) * 72 + tn * 16 + l15] = (f16)S[tm][tn][reg];
    asm volatile("s_waitcnt lgkmcnt(0)" ::: "memory");

    // O += P @ V
#pragma unroll
    for (int ks = 0; ks < 2; ks++) {
      f16x8 pa[2];
#pragma unroll
      for (int tm = 0; tm < 2; tm++)
        pa[tm] = *(const f16x8*)&Pw[(tm * 16 + l15) * 72 + ks * 32 + quad * 8];
      __builtin_amdgcn_s_setprio(1);
#pragma unroll
      for (int tn = 0; tn < 8; tn++) {
        int phys = (ks * 4 + quad + r7) & 7;
        f16x8 vb = *(const f16x8*)&VTs[(tn * 16 + l15) * 64 + phys * 8];
#pragma unroll
        for (int tm = 0; tm < 2; tm++)
          O[tm][tn] = __builtin_amdgcn_mfma_f32_16x16x32_f16(pa[tm], vb, O[tm][tn], 0, 0, 0);
      }
      __builtin_amdgcn_s_setprio(0);
    }
    __syncthreads();
  }

  // epilogue: O / l -> ctx [B*M, H]
#pragma unroll
  for (int tm = 0; tm < 2; tm++)
#pragma unroll
    for (int reg = 0; reg < 4; reg++) {
      float inv = 1.f / lrow[tm][reg];
      int row = bb * SEQ + qrow0 + tm * 16 + quad * 4 + reg;
#pragma unroll
      for (int tn = 0; tn < 8; tn++) {
        int col = h * 128 + tn * 16 + l15;
        ctx[(size_t)row * HDIM + col] = (f16)(O[tm][tn][reg] * inv);
      }
    }
}

// ---------------- launch ----------------

extern "C" void kernel_launch(void* const* d_in, const int* in_sizes, int n_in,
                              void* d_out, int out_size, void* d_ws, size_t ws_size,
                              hipStream_t stream) {
  (void)in_sizes; (void)n_in; (void)out_size; (void)ws_size;
  const float* x      = (const float*)d_in[0];
  const float* conv_w = (const float*)d_in[1];
  const float* conv_b = (const float*)d_in[2];
  const float* w1     = (const float*)d_in[3];
  const float* b1     = (const float*)d_in[4];
  const float* w2     = (const float*)d_in[5];
  const float* b2     = (const float*)d_in[6];
  const float* ln_g   = (const float*)d_in[7];
  const float* ln_b   = (const float*)d_in[8];
  const float* wq     = (const float*)d_in[9];
  const float* bq     = (const float*)d_in[10];
  const float* wk     = (const float*)d_in[11];
  const float* bk     = (const float*)d_in[12];
  const float* wv     = (const float*)d_in[13];
  const float* bv     = (const float*)d_in[14];
  const float* wo     = (const float*)d_in[15];
  const float* bo     = (const float*)d_in[16];
  const float* wp     = (const float*)d_in[17];
  const float* bp     = (const float*)d_in[18];
  float* out = (float*)d_out;

  char* ws = (char*)d_ws;
  size_t off = 0;
  auto alloc = [&](size_t bytes) {
    char* p = ws + off;
    off += (bytes + 255) & ~(size_t)255;
    return p;
  };
  float* cs    = (float*)alloc(8);
  f16* w1T     = (f16*)alloc((size_t)1024 * 512 * 2);
  f16* w2T     = (f16*)alloc((size_t)1024 * 1024 * 2);
  f16* qkvT    = (f16*)alloc((size_t)3072 * 1024 * 2);
  f16* wpT     = (f16*)alloc((size_t)1024 * 1024 * 2);
  f16* woh     = (f16*)alloc((size_t)1024 * 1024 * 2);
  f16* woPT    = (f16*)alloc((size_t)1024 * 1024 * 2);
  float* bqkv  = (float*)alloc((size_t)3072 * 4);
  float* bp2   = (float*)alloc((size_t)1024 * 4);
  float* part  = (float*)alloc((size_t)8 * 1024 * 4);
  f16* qkvQK   = (f16*)alloc((size_t)MR * QK_LD * 2);  // 128 MB; front reused as xh
  f16* h1      = (f16*)alloc((size_t)MR * 1024 * 2);   // 64 MB; reused as vT
  f16* x_norm  = (f16*)alloc((size_t)MR * 1024 * 2);   // 64 MB; reused as ctx
  f16* x_regh  = (f16*)alloc((size_t)MR * 1024 * 2);   // 64 MB (residual + LN input)
  f16* xh = qkvQK;    // [32768,512] dead before qkvQK written
  f16* vT = h1;       // h1 dead after w2 gemm
  f16* ctx = x_norm;  // x_norm dead after QKV gemms

  dim3 tb(32, 8);
  conv_reduce<<<1, 256, 0, stream>>>(conv_w, conv_b, cs);
  transpose_cast<<<dim3(32, 16), tb, 0, stream>>>(w1, w1T, 512, 1024);
  transpose_cast5<<<dim3(32, 32, 5), tb, 0, stream>>>(
      w2, wq, wk, wv, wp,
      w2T, qkvT, qkvT + (size_t)1024 * 1024, qkvT + (size_t)2048 * 1024, wpT);
  cast_f16<<<1024, 256, 0, stream>>>(wo, woh);
  concat_bias<<<12, 256, 0, stream>>>(bq, bk, bv, bqkv);
  fuse_bias_p1<<<dim3(4, 8), 256, 0, stream>>>(bo, wp, part);
  fuse_bias_p2<<<4, 256, 0, stream>>>(part, bp, bp2);
  prep_x<<<16384, 256, 0, stream>>>(x, cs, xh);

  // woPT[n][k] = (wo@wp)[k][n]
  gemm_nt<4><<<dim3(64), 256, 0, stream>>>(wpT, woh, nullptr, (void*)woPT, 1024, 1024, nullptr, nullptr);

  gemm_nt<0><<<dim3(256 * 8), 256, 0, stream>>>(xh, w1T, b1, (void*)h1, 1024, 512, nullptr, nullptr);
  gemm_nt<1><<<dim3(256 * 8), 256, 0, stream>>>(h1, w2T, b2, (void*)x_regh, 1024, 1024, nullptr, nullptr);
  ln_kernel<<<32768, 256, 0, stream>>>(x_regh, ln_g, ln_b, x_norm);
  // QK: N == QK_LD == 2048, plain f16 epilogue lands q,k packed at LD 2048
  gemm_nt<1><<<dim3(256 * 16), 256, 0, stream>>>(x_norm, qkvT, bqkv, (void*)qkvQK, 2048, 1024, nullptr, nullptr);
  // V: straight to vT layout
  gemm_nt<7><<<dim3(256 * 8), 256, 0, stream>>>(x_norm, qkvT + (size_t)2048 * 1024, bqkv + 2048,
                                                nullptr, 1024, 1024, nullptr, vT);
  attn_kernel<<<1024, 512, 0, stream>>>(qkvQK, vT, ctx);
  // fused wo+wp: out = ctx @ woP + bp2 + x_reg
  gemm_nt<5><<<dim3(256 * 8), 256, 0, stream>>>(ctx, woPT, bp2, (void*)out, 1024, 1024, x_regh, nullptr);
}

// Round 4
// 854.193 us; speedup vs baseline: 1.0732x; 1.0732x over previous
//
#include <hip/hip_runtime.h>
#include <hip/hip_fp16.h>
#include <cstdint>
#include <cstddef>

typedef _Float16 f16;
typedef _Float16 f16x8 __attribute__((ext_vector_type(8)));
typedef _Float16 f16x4 __attribute__((ext_vector_type(4)));
typedef _Float16 f16x2 __attribute__((ext_vector_type(2)));
typedef float f32x4 __attribute__((ext_vector_type(4)));
typedef unsigned int ui4 __attribute__((ext_vector_type(4)));

#define NB 64
#define SEQ 512
#define HDIM 1024
#define NHEAD 8
#define HD 128
#define MR (NB * SEQ)      // 32768 rows
#define QK_LD 2048         // q,k packed rows (v goes straight to vT)

// async 16B/lane global->LDS. LDS dest = wave-uniform base + lane*16.
__device__ __forceinline__ void async_copy16(const f16* g, f16* l) {
  __builtin_amdgcn_global_load_lds(
      (__attribute__((address_space(1))) void*)(void*)const_cast<f16*>(g),
      (__attribute__((address_space(3))) void*)l, 16, 0, 0);
}

// ---------------- small prep kernels ----------------

__global__ __launch_bounds__(256) void conv_reduce(
    const float* __restrict__ cw, const float* __restrict__ cb,
    float* __restrict__ out2) {
  int t = threadIdx.x;
  float a = 0.f, b = 0.f;
  for (int i = t; i < HDIM; i += 256) { a += cw[i]; b += cb[i]; }
  for (int m = 32; m >= 1; m >>= 1) { a += __shfl_xor(a, m); b += __shfl_xor(b, m); }
  __shared__ float sa[4], sb[4];
  if ((t & 63) == 0) { sa[t >> 6] = a; sb[t >> 6] = b; }
  __syncthreads();
  if (t == 0) {
    out2[0] = (sa[0] + sa[1] + sa[2] + sa[3]) * (1.f / HDIM);
    out2[1] = (sb[0] + sb[1] + sb[2] + sb[3]) * (1.f / HDIM);
  }
}

// y = x*(1+mean(conv_w)) + mean(conv_b), cast f16. 4 elems/thread.
__global__ __launch_bounds__(256) void prep_x(
    const float* __restrict__ x, const float* __restrict__ cs,
    f16* __restrict__ xh) {
  size_t i = (size_t)blockIdx.x * 256 + threadIdx.x;
  float cw = 1.f + cs[0], cb = cs[1];
  float4 v = ((const float4*)x)[i];
  f16x4 o;
  o[0] = (f16)(v.x * cw + cb);
  o[1] = (f16)(v.y * cw + cb);
  o[2] = (f16)(v.z * cw + cb);
  o[3] = (f16)(v.w * cw + cb);
  ((f16x4*)xh)[i] = o;
}

__global__ __launch_bounds__(256) void concat_bias(
    const float* __restrict__ bq, const float* __restrict__ bk,
    const float* __restrict__ bv, float* __restrict__ dst) {
  int i = blockIdx.x * 256 + threadIdx.x;  // 3072
  if (i < 1024) dst[i] = bq[i];
  else if (i < 2048) dst[i] = bk[i - 1024];
  else dst[i] = bv[i - 2048];
}

// fp32 -> f16 elementwise (no transpose), 4 elems/thread
__global__ __launch_bounds__(256) void cast_f16(
    const float* __restrict__ src, f16* __restrict__ dst) {
  size_t i = (size_t)blockIdx.x * 256 + threadIdx.x;
  float4 v = ((const float4*)src)[i];
  f16x4 o;
  o[0] = (f16)v.x; o[1] = (f16)v.y; o[2] = (f16)v.z; o[3] = (f16)v.w;
  ((f16x4*)dst)[i] = o;
}

// phase1: partial[jc][n] = sum_{j in chunk jc} bo[j]*wp[j][n];  grid (4, 8)
__global__ __launch_bounds__(256) void fuse_bias_p1(
    const float* __restrict__ bo, const float* __restrict__ wp,
    float* __restrict__ partial) {
  int n = blockIdx.x * 256 + threadIdx.x;
  int jc = blockIdx.y;
  float s = 0.f;
#pragma unroll 8
  for (int j = jc * 128; j < jc * 128 + 128; j++) s += bo[j] * wp[(size_t)j * 1024 + n];
  partial[(size_t)jc * 1024 + n] = s;
}

// phase2: bp2[n] = bp[n] + sum_jc partial[jc][n];  grid 4
__global__ __launch_bounds__(256) void fuse_bias_p2(
    const float* __restrict__ partial, const float* __restrict__ bp,
    float* __restrict__ bp2) {
  int n = blockIdx.x * 256 + threadIdx.x;
  float s = bp[n];
#pragma unroll
  for (int jc = 0; jc < 8; jc++) s += partial[(size_t)jc * 1024 + n];
  bp2[n] = s;
}

// W [K,N] fp32 -> WT [N,K] f16 (NT-gemm weight layout)
__global__ __launch_bounds__(256) void transpose_cast(
    const float* __restrict__ src, f16* __restrict__ dst, int K, int N) {
  __shared__ float tile[32][33];
  int tx = threadIdx.x, ty = threadIdx.y;
  int n0 = blockIdx.x * 32, k0 = blockIdx.y * 32;
#pragma unroll
  for (int r = 0; r < 32; r += 8) tile[ty + r][tx] = src[(size_t)(k0 + ty + r) * N + n0 + tx];
  __syncthreads();
#pragma unroll
  for (int r = 0; r < 32; r += 8)
    dst[(size_t)(n0 + ty + r) * K + k0 + tx] = (f16)tile[tx][ty + r];
}

// five 1024x1024 transpose_casts in one launch; z selects (src,dst)
__global__ __launch_bounds__(256) void transpose_cast5(
    const float* s0, const float* s1, const float* s2, const float* s3, const float* s4,
    f16* d0, f16* d1, f16* d2, f16* d3, f16* d4) {
  const float* src; f16* dst;
  switch (blockIdx.z) {
    case 0: src = s0; dst = d0; break;
    case 1: src = s1; dst = d1; break;
    case 2: src = s2; dst = d2; break;
    case 3: src = s3; dst = d3; break;
    default: src = s4; dst = d4; break;
  }
  __shared__ float tile[32][33];
  int tx = threadIdx.x, ty = threadIdx.y;
  int n0 = blockIdx.x * 32, k0 = blockIdx.y * 32;
#pragma unroll
  for (int r = 0; r < 32; r += 8) tile[ty + r][tx] = src[(size_t)(k0 + ty + r) * 1024 + n0 + tx];
  __syncthreads();
#pragma unroll
  for (int r = 0; r < 32; r += 8)
    dst[(size_t)(n0 + ty + r) * 1024 + k0 + tx] = (f16)tile[tx][ty + r];
}

// LayerNorm over H=1024, f16 in (x_regh), f16 out (x_norm)
__global__ __launch_bounds__(256) void ln_kernel(
    const f16* __restrict__ xin, const float* __restrict__ g,
    const float* __restrict__ bta, f16* __restrict__ out) {
  int row = blockIdx.x;
  int t = threadIdx.x;
  f16x4 vh = ((const f16x4*)(xin + (size_t)row * HDIM))[t];
  float vx = (float)vh[0], vy = (float)vh[1], vz = (float)vh[2], vw = (float)vh[3];
  float s = vx + vy + vz + vw;
  float s2 = vx * vx + vy * vy + vz * vz + vw * vw;
  for (int m = 32; m >= 1; m >>= 1) { s += __shfl_xor(s, m); s2 += __shfl_xor(s2, m); }
  __shared__ float sa[4], sb[4];
  if ((t & 63) == 0) { sa[t >> 6] = s; sb[t >> 6] = s2; }
  __syncthreads();
  float S = sa[0] + sa[1] + sa[2] + sa[3];
  float S2 = sb[0] + sb[1] + sb[2] + sb[3];
  float mu = S * (1.f / HDIM);
  float var = S2 * (1.f / HDIM) - mu * mu;
  float inv = rsqrtf(var + 1e-5f);
  float4 gv = ((const float4*)g)[t];
  float4 bv = ((const float4*)bta)[t];
  f16x4 o;
  o[0] = (f16)((vx - mu) * inv * gv.x + bv.x);
  o[1] = (f16)((vy - mu) * inv * gv.y + bv.y);
  o[2] = (f16)((vz - mu) * inv * gv.z + bv.z);
  o[3] = (f16)((vw - mu) * inv * gv.w + bv.w);
  ((f16x4*)(out + (size_t)row * HDIM))[t] = o;
}

// ---------------- main NT GEMM: C[M,N] = A[M,K] @ BT[N,K]^T + bias ----------------
// 512 threads / 8 waves (2x4 grid, wave tile 64x32), 128x128 block tile, BK=64.
// Rotated global_load_lds staging (bank-floor b128 reads, verified conflict-free).
// R0-proven configuration (858 TF, MfmaUtil 40%) -- do not touch.
// EPI: 0 relu->f16 | 1 f16 | 4 f16 no-bias | 5 fp32 = acc+bias+(float)Xres (residual)
//      6 QKV: cols<2048 -> f16 @ LD 2048; cols>=2048 -> V written to vT layout
template <int EPI>
__global__ __launch_bounds__(512) void gemm_nt(
    const f16* __restrict__ A, const f16* __restrict__ BT,
    const float* __restrict__ bias, void* __restrict__ Cout, int N, int K,
    const f16* __restrict__ Xres, f16* __restrict__ vTout) {
  __shared__ __align__(16) f16 As[128 * 64];
  __shared__ __align__(16) f16 Bs[128 * 64];
  const int tid = threadIdx.x;
  const int wave = tid >> 6, lane = tid & 63;
  const int l15 = lane & 15, quad = lane >> 4;

  // block swizzle: groups of up to 16 bm, bn inner
  const int gn = N >> 7;
  const int gm = (int)gridDim.x / gn;
  const int pid = blockIdx.x;
  const int npg = 16 * gn;
  const int gid = pid / npg;
  const int rem = pid - gid * npg;
  const int grows = min(16, gm - gid * 16);
  const int bm = gid * 16 + rem % grows;
  const int bn = rem / grows;

  const int wm = wave >> 2, wn = wave & 3;   // 2 x 4 wave grid; wave tile 64x32

  f32x4 z4 = {0.f, 0.f, 0.f, 0.f};
  f32x4 acc[4][2];
#pragma unroll
  for (int i = 0; i < 4; i++)
#pragma unroll
    for (int j = 0; j < 2; j++) acc[i][j] = z4;

  // staging: row = tid>>3 (0..63), phys chunk p = tid&7, logical c = (p - row&7)&7
  const int srow = tid >> 3;
  const int c = ((tid & 7) - (srow & 7)) & 7;
  const f16* Ag = A + (size_t)(bm * 128 + srow) * K + c * 8;
  const f16* Bg = BT + (size_t)(bn * 128 + srow) * K + c * 8;
  f16* Al0 = As + tid * 8;
  f16* Al1 = As + 64 * 64 + tid * 8;
  f16* Bl0 = Bs + tid * 8;
  f16* Bl1 = Bs + 64 * 64 + tid * 8;
  const size_t kstep = (size_t)64 * K;

  const int r7 = l15 & 7;  // fragment-row rotation

  for (int k0 = 0; k0 < K; k0 += 64) {
    async_copy16(Ag, Al0);
    async_copy16(Ag + kstep, Al1);
    async_copy16(Bg, Bl0);
    async_copy16(Bg + kstep, Bl1);
    Ag += 64; Bg += 64;
    __syncthreads();
#pragma unroll
    for (int s = 0; s < 2; s++) {
      f16x8 af[4], bfr[2];
#pragma unroll
      for (int t = 0; t < 4; t++) {
        int phys = (s * 4 + quad + r7) & 7;
        af[t] = *(const f16x8*)&As[(wm * 64 + t * 16 + l15) * 64 + phys * 8];
      }
#pragma unroll
      for (int u = 0; u < 2; u++) {
        int phys = (s * 4 + quad + r7) & 7;
        bfr[u] = *(const f16x8*)&Bs[(wn * 32 + u * 16 + l15) * 64 + phys * 8];
      }
#pragma unroll
      for (int i = 0; i < 4; i++)
#pragma unroll
        for (int j = 0; j < 2; j++)
          acc[i][j] = __builtin_amdgcn_mfma_f32_16x16x32_f16(af[i], bfr[j], acc[i][j], 0, 0, 0);
    }
    __syncthreads();
  }

  float* Cf = (float*)Cout;
  f16* Ch = (f16*)Cout;
#pragma unroll
  for (int i = 0; i < 4; i++) {
    int r0 = bm * 128 + wm * 64 + i * 16 + quad * 4;
#pragma unroll
    for (int j = 0; j < 2; j++) {
      int c0 = bn * 128 + wn * 32 + j * 16;
      int cc = c0 + l15;
      float bv = (EPI == 4) ? 0.f : bias[cc];
      if (EPI == 6 && c0 >= 2048) {
        // V part -> vT[(b*8+h)*128 + d][m], 4 consecutive m per lane
        int hh = (cc - 2048) >> 7, d = (cc - 2048) & 127;
        int bb = r0 >> 9, ml = r0 & 511;
        f16x4 o;
#pragma unroll
        for (int reg = 0; reg < 4; reg++) o[reg] = (f16)(acc[i][j][reg] + bv);
        *(f16x4*)&vTout[((size_t)(bb * NHEAD + hh) * HD + d) * SEQ + ml] = o;
      } else {
#pragma unroll
        for (int reg = 0; reg < 4; reg++) {
          float v = acc[i][j][reg] + bv;
          if (EPI == 0)      Ch[(size_t)(r0 + reg) * N + cc] = (f16)fmaxf(v, 0.f);
          else if (EPI == 1) Ch[(size_t)(r0 + reg) * N + cc] = (f16)v;
          else if (EPI == 4) Ch[(size_t)(r0 + reg) * N + cc] = (f16)v;
          else if (EPI == 5) {
            size_t idx = (size_t)(r0 + reg) * N + cc;
            Cf[idx] = v + (float)Xres[idx];
          } else {  // EPI == 6, q/k part, LD 2048
            Ch[(size_t)(r0 + reg) * QK_LD + cc] = (f16)v;
          }
        }
      }
    }
  }
}

// ---------------- flash attention, T12 in-register softmax ----------------
// grid: 1024 = bh(512) x qc(2).  512 thr / 8 waves; wave owns 32 q-rows.
// SWAPPED QK^T: ST = mfma(K-frag, Q-frag) -> lane holds P[key=quad*4+reg+tn*16]
// [qrow=l15].  Row-sum = 16 local adds + shfl_xor(16,32).  P -> PV A-fragment
// entirely in registers: f16 pack (RTN, matches old numerics) + v_permlane32_swap
// + shfl_xor(16) + quad-parity selects (word mapping verified against the
// 16x16x32 A-frag key layout).  No Ps LDS, no lgkm drain, no P round-trip.
// lrow kept in l15-layout, redistributed once at epilogue via 8 bpermutes.
__global__ __launch_bounds__(512) void attn_kernel(
    const f16* __restrict__ qkv, const f16* __restrict__ vT,
    f16* __restrict__ ctx) {
  const int tid = threadIdx.x;
  const int wave = tid >> 6, lane = tid & 63;
  const int l15 = lane & 15, quad = lane >> 4;
  const int bidx = blockIdx.x;
  const int qc = bidx >> 9;            // siblings 512 apart -> same XCD, co-resident
  const int bh = bidx & 511;
  const int h = bh & 7, bb = bh >> 3;

  const f16* Qbase = qkv + (size_t)(bb * SEQ) * QK_LD + h * 128;
  const f16* Kbase = Qbase + 1024;
  const f16* VTbase = vT + (size_t)(bb * NHEAD + h) * HD * SEQ;

  __shared__ __align__(16) f16 Ks[64 * 128];    // rotated chunks
  __shared__ __align__(16) f16 VTs[128 * 64];   // rotated chunks

  const float scale = 0.08838834764831845f;  // 1/sqrt(128)
  const int qrow0 = qc * 256 + wave * 32;
  f16x8 qf[2][4];
#pragma unroll
  for (int tm = 0; tm < 2; tm++)
#pragma unroll
    for (int s = 0; s < 4; s++) {
      qf[tm][s] = *(const f16x8*)(Qbase + (size_t)(qrow0 + tm * 16 + l15) * QK_LD + s * 32 + quad * 8);
#pragma unroll
      for (int e = 0; e < 8; e++) qf[tm][s][e] *= (f16)scale;
    }

  f32x4 z4 = {0.f, 0.f, 0.f, 0.f};
  f32x4 O[2][8];
#pragma unroll
  for (int i = 0; i < 2; i++)
#pragma unroll
    for (int j = 0; j < 8; j++) O[i][j] = z4;
  float lrow[2] = {0.f, 0.f};   // row-sum for qrow = qrow0 + tm*16 + l15

  // K staging: row = 32*i + (tid>>4), p = tid&15, c = (p - row&15)&15
  const int kc = ((tid & 15) - ((tid >> 4) & 15)) & 15;
  const f16* Kg = Kbase + (size_t)(tid >> 4) * QK_LD + kc * 8;
  f16* Kl = Ks + tid * 8;
  // VT staging: row = 64*i + (tid>>3), p = tid&7, c = (p - row&7)&7
  const int vc = ((tid & 7) - ((tid >> 3) & 7)) & 7;
  const f16* Vg = VTbase + (size_t)(tid >> 3) * SEQ + vc * 8;
  f16* Vl = VTs + tid * 8;

  const int r7 = l15 & 7;
  const bool qodd = (quad & 1) != 0;

  for (int kt = 0; kt < 8; kt++) {
    const int krow0 = kt * 64;
#pragma unroll
    for (int i = 0; i < 2; i++)
      async_copy16(Kg + (size_t)(krow0 + 32 * i) * QK_LD, Kl + 4096 * i);
#pragma unroll
    for (int i = 0; i < 2; i++)
      async_copy16(Vg + (size_t)(64 * i) * SEQ + krow0, Vl + 4096 * i);
    __syncthreads();

    // ST = K-tile @ Q^T (swapped): ST[tn][tm] reg -> key=krow0+tn*16+quad*4+reg,
    // qrow = qrow0 + tm*16 + l15
    f32x4 ST[4][2];
#pragma unroll
    for (int i = 0; i < 4; i++)
#pragma unroll
      for (int j = 0; j < 2; j++) ST[i][j] = z4;
#pragma unroll
    for (int s = 0; s < 4; s++) {
      f16x8 bfr[4];
#pragma unroll
      for (int tn = 0; tn < 4; tn++) {
        int phys = (s * 4 + quad + l15) & 15;
        bfr[tn] = *(const f16x8*)&Ks[(tn * 16 + l15) * 128 + phys * 8];
      }
      __builtin_amdgcn_s_setprio(1);
#pragma unroll
      for (int tn = 0; tn < 4; tn++)
#pragma unroll
        for (int tm = 0; tm < 2; tm++)
          ST[tn][tm] = __builtin_amdgcn_mfma_f32_16x16x32_f16(bfr[tn], qf[tm][s], ST[tn][tm], 0, 0, 0);
      __builtin_amdgcn_s_setprio(0);
    }

    // softmax (fixed-max, diag->1) + in-register P->A-frag pack
    f16x8 pa[2][2];   // [tm][ks]
#pragma unroll
    for (int tm = 0; tm < 2; tm++) {
      const int qg = qrow0 + tm * 16 + l15;
      float rs = 0.f;
      unsigned int H[4][2];
#pragma unroll
      for (int tn = 0; tn < 4; tn++) {
        float p[4];
#pragma unroll
        for (int reg = 0; reg < 4; reg++) {
          int kg = krow0 + tn * 16 + quad * 4 + reg;
          float v = (kg == qg) ? 1.f : __expf(ST[tn][tm][reg]);
          p[reg] = v;
          rs += v;
        }
        f16x2 h01 = {(f16)p[0], (f16)p[1]};
        f16x2 h23 = {(f16)p[2], (f16)p[3]};
        H[tn][0] = __builtin_bit_cast(unsigned int, h01);
        H[tn][1] = __builtin_bit_cast(unsigned int, h23);
      }
      rs += __shfl_xor(rs, 16);
      rs += __shfl_xor(rs, 32);
      lrow[tm] += rs;

      // pa[tm][ks] word w holds keys ks*32 + quad*8 + 2w,2w+1
#pragma unroll
      for (int ks = 0; ks < 2; ks++) {
        unsigned int a0 = H[ks * 2][0], a1 = H[ks * 2][1];
        unsigned int b0 = H[ks * 2 + 1][0], b1 = H[ks * 2 + 1][1];
        // in-place 32-lane half swap: a' = {a.lo, b.lo}, b' = {a.hi, b.hi}
        asm volatile("s_nop 1\n\tv_permlane32_swap_b32 %0, %1\n\ts_nop 1"
                     : "+v"(a0), "+v"(b0));
        asm volatile("s_nop 1\n\tv_permlane32_swap_b32 %0, %1\n\ts_nop 1"
                     : "+v"(a1), "+v"(b1));
        unsigned int c0 = (unsigned int)__shfl_xor((int)a0, 16);
        unsigned int c1 = (unsigned int)__shfl_xor((int)a1, 16);
        unsigned int d0 = (unsigned int)__shfl_xor((int)b0, 16);
        unsigned int d1 = (unsigned int)__shfl_xor((int)b1, 16);
        ui4 wv;
        wv[0] = qodd ? d0 : a0;
        wv[1] = qodd ? d1 : a1;
        wv[2] = qodd ? b0 : c0;
        wv[3] = qodd ? b1 : c1;
        pa[tm][ks] = __builtin_bit_cast(f16x8, wv);
      }
    }

    // O += P @ V
#pragma unroll
    for (int ks = 0; ks < 2; ks++) {
      __builtin_amdgcn_s_setprio(1);
#pragma unroll
      for (int tn = 0; tn < 8; tn++) {
        int phys = (ks * 4 + quad + r7) & 7;
        f16x8 vb = *(const f16x8*)&VTs[(tn * 16 + l15) * 64 + phys * 8];
#pragma unroll
        for (int tm = 0; tm < 2; tm++)
          O[tm][tn] = __builtin_amdgcn_mfma_f32_16x16x32_f16(pa[tm][ks], vb, O[tm][tn], 0, 0, 0);
      }
      __builtin_amdgcn_s_setprio(0);
    }
    __syncthreads();
  }

  // epilogue: redistribute lrow (l15-layout -> quad*4+reg layout), O/l -> ctx
#pragma unroll
  for (int tm = 0; tm < 2; tm++)
#pragma unroll
    for (int reg = 0; reg < 4; reg++) {
      float lv = __shfl(lrow[tm], quad * 4 + reg);
      float inv = 1.f / lv;
      int row = bb * SEQ + qrow0 + tm * 16 + quad * 4 + reg;
#pragma unroll
      for (int tn = 0; tn < 8; tn++) {
        int col = h * 128 + tn * 16 + l15;
        ctx[(size_t)row * HDIM + col] = (f16)(O[tm][tn][reg] * inv);
      }
    }
}

// ---------------- launch ----------------

extern "C" void kernel_launch(void* const* d_in, const int* in_sizes, int n_in,
                              void* d_out, int out_size, void* d_ws, size_t ws_size,
                              hipStream_t stream) {
  (void)in_sizes; (void)n_in; (void)out_size; (void)ws_size;
  const float* x      = (const float*)d_in[0];
  const float* conv_w = (const float*)d_in[1];
  const float* conv_b = (const float*)d_in[2];
  const float* w1     = (const float*)d_in[3];
  const float* b1     = (const float*)d_in[4];
  const float* w2     = (const float*)d_in[5];
  const float* b2     = (const float*)d_in[6];
  const float* ln_g   = (const float*)d_in[7];
  const float* ln_b   = (const float*)d_in[8];
  const float* wq     = (const float*)d_in[9];
  const float* bq     = (const float*)d_in[10];
  const float* wk     = (const float*)d_in[11];
  const float* bk     = (const float*)d_in[12];
  const float* wv     = (const float*)d_in[13];
  const float* bv     = (const float*)d_in[14];
  const float* wo     = (const float*)d_in[15];
  const float* bo     = (const float*)d_in[16];
  const float* wp     = (const float*)d_in[17];
  const float* bp     = (const float*)d_in[18];
  float* out = (float*)d_out;

  char* ws = (char*)d_ws;
  size_t off = 0;
  auto alloc = [&](size_t bytes) {
    char* p = ws + off;
    off += (bytes + 255) & ~(size_t)255;
    return p;
  };
  float* cs    = (float*)alloc(8);
  f16* w1T     = (f16*)alloc((size_t)1024 * 512 * 2);
  f16* w2T     = (f16*)alloc((size_t)1024 * 1024 * 2);
  f16* qkvT    = (f16*)alloc((size_t)3072 * 1024 * 2);
  f16* wpT     = (f16*)alloc((size_t)1024 * 1024 * 2);
  f16* woh     = (f16*)alloc((size_t)1024 * 1024 * 2);
  f16* woPT    = (f16*)alloc((size_t)1024 * 1024 * 2);
  float* bqkv  = (float*)alloc((size_t)3072 * 4);
  float* bp2   = (float*)alloc((size_t)1024 * 4);
  float* part  = (float*)alloc((size_t)8 * 1024 * 4);
  f16* qkvQK   = (f16*)alloc((size_t)MR * QK_LD * 2);  // 128 MB; front reused as xh
  f16* h1      = (f16*)alloc((size_t)MR * 1024 * 2);   // 64 MB; reused as vT
  f16* x_norm  = (f16*)alloc((size_t)MR * 1024 * 2);   // 64 MB; reused as ctx
  f16* x_regh  = (f16*)alloc((size_t)MR * 1024 * 2);   // 64 MB (residual + LN input)
  f16* xh = qkvQK;    // [32768,512] dead before qkvQK written
  f16* vT = h1;       // h1 dead after w2 gemm
  f16* ctx = x_norm;  // x_norm dead after QKV gemm

  dim3 tb(32, 8);
  conv_reduce<<<1, 256, 0, stream>>>(conv_w, conv_b, cs);
  transpose_cast<<<dim3(32, 16), tb, 0, stream>>>(w1, w1T, 512, 1024);
  transpose_cast5<<<dim3(32, 32, 5), tb, 0, stream>>>(
      w2, wq, wk, wv, wp,
      w2T, qkvT, qkvT + (size_t)1024 * 1024, qkvT + (size_t)2048 * 1024, wpT);
  cast_f16<<<1024, 256, 0, stream>>>(wo, woh);
  concat_bias<<<12, 256, 0, stream>>>(bq, bk, bv, bqkv);
  fuse_bias_p1<<<dim3(4, 8), 256, 0, stream>>>(bo, wp, part);
  fuse_bias_p2<<<4, 256, 0, stream>>>(part, bp, bp2);
  prep_x<<<16384, 256, 0, stream>>>(x, cs, xh);

  // woPT[n][k] = (wo@wp)[k][n]
  gemm_nt<4><<<dim3(64), 512, 0, stream>>>(wpT, woh, nullptr, (void*)woPT, 1024, 1024, nullptr, nullptr);

  gemm_nt<0><<<dim3(256 * 8), 512, 0, stream>>>(xh, w1T, b1, (void*)h1, 1024, 512, nullptr, nullptr);
  gemm_nt<1><<<dim3(256 * 8), 512, 0, stream>>>(h1, w2T, b2, (void*)x_regh, 1024, 1024, nullptr, nullptr);
  ln_kernel<<<32768, 256, 0, stream>>>(x_regh, ln_g, ln_b, x_norm);
  // QKV: q,k -> qkvQK (LD 2048); v -> vT directly
  gemm_nt<6><<<dim3(256 * 24), 512, 0, stream>>>(x_norm, qkvT, bqkv, (void*)qkvQK, 3072, 1024, nullptr, vT);
  attn_kernel<<<1024, 512, 0, stream>>>(qkvQK, vT, ctx);
  // fused wo+wp: out = ctx @ woP + bp2 + x_reg
  gemm_nt<5><<<dim3(256 * 8), 512, 0, stream>>>(ctx, woPT, bp2, (void*)out, 1024, 1024, x_regh, nullptr);
}

// Round 5
// 853.903 us; speedup vs baseline: 1.0735x; 1.0003x over previous
//
#include <hip/hip_runtime.h>
#include <hip/hip_fp16.h>
#include <cstdint>
#include <cstddef>

typedef _Float16 f16;
typedef _Float16 f16x8 __attribute__((ext_vector_type(8)));
typedef _Float16 f16x4 __attribute__((ext_vector_type(4)));
typedef _Float16 f16x2 __attribute__((ext_vector_type(2)));
typedef float f32x4 __attribute__((ext_vector_type(4)));
typedef unsigned int ui4 __attribute__((ext_vector_type(4)));

#define NB 64
#define SEQ 512
#define HDIM 1024
#define NHEAD 8
#define HD 128
#define MR (NB * SEQ)      // 32768 rows
#define QK_LD 2048         // q,k packed rows (v goes straight to vT)

// async 16B/lane global->LDS. LDS dest = wave-uniform base + lane*16.
__device__ __forceinline__ void async_copy16(const f16* g, f16* l) {
  __builtin_amdgcn_global_load_lds(
      (__attribute__((address_space(1))) void*)(void*)const_cast<f16*>(g),
      (__attribute__((address_space(3))) void*)l, 16, 0, 0);
}

// ---------------- small prep kernels ----------------

__global__ __launch_bounds__(256) void conv_reduce(
    const float* __restrict__ cw, const float* __restrict__ cb,
    float* __restrict__ out2) {
  int t = threadIdx.x;
  float a = 0.f, b = 0.f;
  for (int i = t; i < HDIM; i += 256) { a += cw[i]; b += cb[i]; }
  for (int m = 32; m >= 1; m >>= 1) { a += __shfl_xor(a, m); b += __shfl_xor(b, m); }
  __shared__ float sa[4], sb[4];
  if ((t & 63) == 0) { sa[t >> 6] = a; sb[t >> 6] = b; }
  __syncthreads();
  if (t == 0) {
    out2[0] = (sa[0] + sa[1] + sa[2] + sa[3]) * (1.f / HDIM);
    out2[1] = (sb[0] + sb[1] + sb[2] + sb[3]) * (1.f / HDIM);
  }
}

// y = x*(1+mean(conv_w)) + mean(conv_b), cast f16. 4 elems/thread.
__global__ __launch_bounds__(256) void prep_x(
    const float* __restrict__ x, const float* __restrict__ cs,
    f16* __restrict__ xh) {
  size_t i = (size_t)blockIdx.x * 256 + threadIdx.x;
  float cw = 1.f + cs[0], cb = cs[1];
  float4 v = ((const float4*)x)[i];
  f16x4 o;
  o[0] = (f16)(v.x * cw + cb);
  o[1] = (f16)(v.y * cw + cb);
  o[2] = (f16)(v.z * cw + cb);
  o[3] = (f16)(v.w * cw + cb);
  ((f16x4*)xh)[i] = o;
}

__global__ __launch_bounds__(256) void concat_bias(
    const float* __restrict__ bq, const float* __restrict__ bk,
    const float* __restrict__ bv, float* __restrict__ dst) {
  int i = blockIdx.x * 256 + threadIdx.x;  // 3072
  if (i < 1024) dst[i] = bq[i];
  else if (i < 2048) dst[i] = bk[i - 1024];
  else dst[i] = bv[i - 2048];
}

// fp32 -> f16 elementwise (no transpose), 4 elems/thread
__global__ __launch_bounds__(256) void cast_f16(
    const float* __restrict__ src, f16* __restrict__ dst) {
  size_t i = (size_t)blockIdx.x * 256 + threadIdx.x;
  float4 v = ((const float4*)src)[i];
  f16x4 o;
  o[0] = (f16)v.x; o[1] = (f16)v.y; o[2] = (f16)v.z; o[3] = (f16)v.w;
  ((f16x4*)dst)[i] = o;
}

// phase1: partial[jc][n] = sum_{j in chunk jc} bo[j]*wp[j][n];  grid (4, 8)
__global__ __launch_bounds__(256) void fuse_bias_p1(
    const float* __restrict__ bo, const float* __restrict__ wp,
    float* __restrict__ partial) {
  int n = blockIdx.x * 256 + threadIdx.x;
  int jc = blockIdx.y;
  float s = 0.f;
#pragma unroll 8
  for (int j = jc * 128; j < jc * 128 + 128; j++) s += bo[j] * wp[(size_t)j * 1024 + n];
  partial[(size_t)jc * 1024 + n] = s;
}

// phase2: bp2[n] = bp[n] + sum_jc partial[jc][n];  grid 4
__global__ __launch_bounds__(256) void fuse_bias_p2(
    const float* __restrict__ partial, const float* __restrict__ bp,
    float* __restrict__ bp2) {
  int n = blockIdx.x * 256 + threadIdx.x;
  float s = bp[n];
#pragma unroll
  for (int jc = 0; jc < 8; jc++) s += partial[(size_t)jc * 1024 + n];
  bp2[n] = s;
}

// W [K,N] fp32 -> WT [N,K] f16 (NT-gemm weight layout)
__global__ __launch_bounds__(256) void transpose_cast(
    const float* __restrict__ src, f16* __restrict__ dst, int K, int N) {
  __shared__ float tile[32][33];
  int tx = threadIdx.x, ty = threadIdx.y;
  int n0 = blockIdx.x * 32, k0 = blockIdx.y * 32;
#pragma unroll
  for (int r = 0; r < 32; r += 8) tile[ty + r][tx] = src[(size_t)(k0 + ty + r) * N + n0 + tx];
  __syncthreads();
#pragma unroll
  for (int r = 0; r < 32; r += 8)
    dst[(size_t)(n0 + ty + r) * K + k0 + tx] = (f16)tile[tx][ty + r];
}

// five 1024x1024 transpose_casts in one launch; z selects (src,dst)
__global__ __launch_bounds__(256) void transpose_cast5(
    const float* s0, const float* s1, const float* s2, const float* s3, const float* s4,
    f16* d0, f16* d1, f16* d2, f16* d3, f16* d4) {
  const float* src; f16* dst;
  switch (blockIdx.z) {
    case 0: src = s0; dst = d0; break;
    case 1: src = s1; dst = d1; break;
    case 2: src = s2; dst = d2; break;
    case 3: src = s3; dst = d3; break;
    default: src = s4; dst = d4; break;
  }
  __shared__ float tile[32][33];
  int tx = threadIdx.x, ty = threadIdx.y;
  int n0 = blockIdx.x * 32, k0 = blockIdx.y * 32;
#pragma unroll
  for (int r = 0; r < 32; r += 8) tile[ty + r][tx] = src[(size_t)(k0 + ty + r) * 1024 + n0 + tx];
  __syncthreads();
#pragma unroll
  for (int r = 0; r < 32; r += 8)
    dst[(size_t)(n0 + ty + r) * 1024 + k0 + tx] = (f16)tile[tx][ty + r];
}

// LayerNorm over H=1024, f16 in (x_regh), f16 out (x_norm)
__global__ __launch_bounds__(256) void ln_kernel(
    const f16* __restrict__ xin, const float* __restrict__ g,
    const float* __restrict__ bta, f16* __restrict__ out) {
  int row = blockIdx.x;
  int t = threadIdx.x;
  f16x4 vh = ((const f16x4*)(xin + (size_t)row * HDIM))[t];
  float vx = (float)vh[0], vy = (float)vh[1], vz = (float)vh[2], vw = (float)vh[3];
  float s = vx + vy + vz + vw;
  float s2 = vx * vx + vy * vy + vz * vz + vw * vw;
  for (int m = 32; m >= 1; m >>= 1) { s += __shfl_xor(s, m); s2 += __shfl_xor(s2, m); }
  __shared__ float sa[4], sb[4];
  if ((t & 63) == 0) { sa[t >> 6] = s; sb[t >> 6] = s2; }
  __syncthreads();
  float S = sa[0] + sa[1] + sa[2] + sa[3];
  float S2 = sb[0] + sb[1] + sb[2] + sb[3];
  float mu = S * (1.f / HDIM);
  float var = S2 * (1.f / HDIM) - mu * mu;
  float inv = rsqrtf(var + 1e-5f);
  float4 gv = ((const float4*)g)[t];
  float4 bv = ((const float4*)bta)[t];
  f16x4 o;
  o[0] = (f16)((vx - mu) * inv * gv.x + bv.x);
  o[1] = (f16)((vy - mu) * inv * gv.y + bv.y);
  o[2] = (f16)((vz - mu) * inv * gv.z + bv.z);
  o[3] = (f16)((vw - mu) * inv * gv.w + bv.w);
  ((f16x4*)(out + (size_t)row * HDIM))[t] = o;
}

// ---------------- main NT GEMM: C[M,N] = A[M,K] @ BT[N,K]^T + bias ----------------
// 512 threads / 8 waves (2x4 grid, wave tile 64x32), 128x128 block tile, BK=64.
// Rotated global_load_lds staging (bank-floor b128 reads, verified conflict-free).
// R0-proven configuration (858 TF, MfmaUtil 40%) -- do not touch.
// EPI: 0 relu->f16 | 1 f16 | 4 f16 no-bias | 5 fp32 = acc+bias+(float)Xres (residual)
//      6 QKV: cols<2048 -> f16 @ LD 2048; cols>=2048 -> V written to vT layout
template <int EPI>
__global__ __launch_bounds__(512) void gemm_nt(
    const f16* __restrict__ A, const f16* __restrict__ BT,
    const float* __restrict__ bias, void* __restrict__ Cout, int N, int K,
    const f16* __restrict__ Xres, f16* __restrict__ vTout) {
  __shared__ __align__(16) f16 As[128 * 64];
  __shared__ __align__(16) f16 Bs[128 * 64];
  const int tid = threadIdx.x;
  const int wave = tid >> 6, lane = tid & 63;
  const int l15 = lane & 15, quad = lane >> 4;

  // block swizzle: groups of up to 16 bm, bn inner
  const int gn = N >> 7;
  const int gm = (int)gridDim.x / gn;
  const int pid = blockIdx.x;
  const int npg = 16 * gn;
  const int gid = pid / npg;
  const int rem = pid - gid * npg;
  const int grows = min(16, gm - gid * 16);
  const int bm = gid * 16 + rem % grows;
  const int bn = rem / grows;

  const int wm = wave >> 2, wn = wave & 3;   // 2 x 4 wave grid; wave tile 64x32

  f32x4 z4 = {0.f, 0.f, 0.f, 0.f};
  f32x4 acc[4][2];
#pragma unroll
  for (int i = 0; i < 4; i++)
#pragma unroll
    for (int j = 0; j < 2; j++) acc[i][j] = z4;

  // staging: row = tid>>3 (0..63), phys chunk p = tid&7, logical c = (p - row&7)&7
  const int srow = tid >> 3;
  const int c = ((tid & 7) - (srow & 7)) & 7;
  const f16* Ag = A + (size_t)(bm * 128 + srow) * K + c * 8;
  const f16* Bg = BT + (size_t)(bn * 128 + srow) * K + c * 8;
  f16* Al0 = As + tid * 8;
  f16* Al1 = As + 64 * 64 + tid * 8;
  f16* Bl0 = Bs + tid * 8;
  f16* Bl1 = Bs + 64 * 64 + tid * 8;
  const size_t kstep = (size_t)64 * K;

  const int r7 = l15 & 7;  // fragment-row rotation

  for (int k0 = 0; k0 < K; k0 += 64) {
    async_copy16(Ag, Al0);
    async_copy16(Ag + kstep, Al1);
    async_copy16(Bg, Bl0);
    async_copy16(Bg + kstep, Bl1);
    Ag += 64; Bg += 64;
    __syncthreads();
#pragma unroll
    for (int s = 0; s < 2; s++) {
      f16x8 af[4], bfr[2];
#pragma unroll
      for (int t = 0; t < 4; t++) {
        int phys = (s * 4 + quad + r7) & 7;
        af[t] = *(const f16x8*)&As[(wm * 64 + t * 16 + l15) * 64 + phys * 8];
      }
#pragma unroll
      for (int u = 0; u < 2; u++) {
        int phys = (s * 4 + quad + r7) & 7;
        bfr[u] = *(const f16x8*)&Bs[(wn * 32 + u * 16 + l15) * 64 + phys * 8];
      }
#pragma unroll
      for (int i = 0; i < 4; i++)
#pragma unroll
        for (int j = 0; j < 2; j++)
          acc[i][j] = __builtin_amdgcn_mfma_f32_16x16x32_f16(af[i], bfr[j], acc[i][j], 0, 0, 0);
    }
    __syncthreads();
  }

  float* Cf = (float*)Cout;
  f16* Ch = (f16*)Cout;
#pragma unroll
  for (int i = 0; i < 4; i++) {
    int r0 = bm * 128 + wm * 64 + i * 16 + quad * 4;
#pragma unroll
    for (int j = 0; j < 2; j++) {
      int c0 = bn * 128 + wn * 32 + j * 16;
      int cc = c0 + l15;
      float bv = (EPI == 4) ? 0.f : bias[cc];
      if (EPI == 6 && c0 >= 2048) {
        // V part -> vT[(b*8+h)*128 + d][m], 4 consecutive m per lane
        int hh = (cc - 2048) >> 7, d = (cc - 2048) & 127;
        int bb = r0 >> 9, ml = r0 & 511;
        f16x4 o;
#pragma unroll
        for (int reg = 0; reg < 4; reg++) o[reg] = (f16)(acc[i][j][reg] + bv);
        *(f16x4*)&vTout[((size_t)(bb * NHEAD + hh) * HD + d) * SEQ + ml] = o;
      } else {
#pragma unroll
        for (int reg = 0; reg < 4; reg++) {
          float v = acc[i][j][reg] + bv;
          if (EPI == 0)      Ch[(size_t)(r0 + reg) * N + cc] = (f16)fmaxf(v, 0.f);
          else if (EPI == 1) Ch[(size_t)(r0 + reg) * N + cc] = (f16)v;
          else if (EPI == 4) Ch[(size_t)(r0 + reg) * N + cc] = (f16)v;
          else if (EPI == 5) {
            size_t idx = (size_t)(r0 + reg) * N + cc;
            Cf[idx] = v + (float)Xres[idx];
          } else {  // EPI == 6, q/k part, LD 2048
            Ch[(size_t)(r0 + reg) * QK_LD + cc] = (f16)v;
          }
        }
      }
    }
  }
}

// ---------------- flash attention, T12 in-register softmax + T14 dbuf staging ----
// grid: 1024 = bh(512) x qc(2).  512 thr / 8 waves; wave owns 32 q-rows.
// SWAPPED QK^T (R4-verified): lane holds P[key][qrow=l15]; softmax + P->A-frag
// pack fully in registers (permlane32_swap + shfl + parity select).
// NEW (T14): K/V LDS double-buffered; stage tile t+1 before computing tile t;
// counted vmcnt(4) keeps next tile's 4 loads in flight across raw s_barrier --
// load latency hides under QK+softmax+PV instead of a per-tile vmcnt(0) drain.
// Race audit: stage at iter t+1 writes buf[t&1], last read in compute(t); the
// end-of-t barrier separates them (ds_read results consumed by MFMA before any
// wave reaches it).  LDS 64 KB -> 2 blocks/CU, 16 waves/CU.
__global__ __launch_bounds__(512) void attn_kernel(
    const f16* __restrict__ qkv, const f16* __restrict__ vT,
    f16* __restrict__ ctx) {
  const int tid = threadIdx.x;
  const int wave = tid >> 6, lane = tid & 63;
  const int l15 = lane & 15, quad = lane >> 4;
  const int bidx = blockIdx.x;
  const int qc = bidx >> 9;            // siblings 512 apart -> same XCD, co-resident
  const int bh = bidx & 511;
  const int h = bh & 7, bb = bh >> 3;

  const f16* Qbase = qkv + (size_t)(bb * SEQ) * QK_LD + h * 128;
  const f16* Kbase = Qbase + 1024;
  const f16* VTbase = vT + (size_t)(bb * NHEAD + h) * HD * SEQ;

  __shared__ __align__(16) f16 Ks[2 * 64 * 128];    // double-buffered, rotated chunks
  __shared__ __align__(16) f16 VTs[2 * 128 * 64];   // double-buffered, rotated chunks

  const float scale = 0.08838834764831845f;  // 1/sqrt(128)
  const int qrow0 = qc * 256 + wave * 32;
  f16x8 qf[2][4];
#pragma unroll
  for (int tm = 0; tm < 2; tm++)
#pragma unroll
    for (int s = 0; s < 4; s++) {
      qf[tm][s] = *(const f16x8*)(Qbase + (size_t)(qrow0 + tm * 16 + l15) * QK_LD + s * 32 + quad * 8);
#pragma unroll
      for (int e = 0; e < 8; e++) qf[tm][s][e] *= (f16)scale;
    }

  f32x4 z4 = {0.f, 0.f, 0.f, 0.f};
  f32x4 O[2][8];
#pragma unroll
  for (int i = 0; i < 2; i++)
#pragma unroll
    for (int j = 0; j < 8; j++) O[i][j] = z4;
  float lrow[2] = {0.f, 0.f};   // row-sum for qrow = qrow0 + tm*16 + l15

  // K staging: row = 32*i + (tid>>4), p = tid&15, c = (p - row&15)&15
  const int kc = ((tid & 15) - ((tid >> 4) & 15)) & 15;
  const f16* Kg = Kbase + (size_t)(tid >> 4) * QK_LD + kc * 8;
  // VT staging: row = 64*i + (tid>>3), p = tid&7, c = (p - row&7)&7
  const int vc = ((tid & 7) - ((tid >> 3) & 7)) & 7;
  const f16* Vg = VTbase + (size_t)(tid >> 3) * SEQ + vc * 8;

  const int r7 = l15 & 7;
  const bool qodd = (quad & 1) != 0;

#define STAGE_KV_(BUF, KT) do {                                               \
    const int kr_ = (KT) * 64;                                                \
    _Pragma("unroll") for (int i_ = 0; i_ < 2; i_++)                          \
      async_copy16(Kg + (size_t)(kr_ + 32 * i_) * QK_LD,                      \
                   Ks + (BUF) * 8192 + tid * 8 + 4096 * i_);                  \
    _Pragma("unroll") for (int i_ = 0; i_ < 2; i_++)                          \
      async_copy16(Vg + (size_t)(64 * i_) * SEQ + kr_,                        \
                   VTs + (BUF) * 8192 + tid * 8 + 4096 * i_);                 \
  } while (0)

  // clean vmcnt base (Q-frag loads retired), then stage tile 0
  asm volatile("s_waitcnt vmcnt(0)" ::: "memory");
  STAGE_KV_(0, 0);

  for (int kt = 0; kt < 8; kt++) {
    const int buf = kt & 1;
    const f16* Ksb = Ks + buf * 8192;
    const f16* VTsb = VTs + buf * 8192;
    const int krow0 = kt * 64;

    if (kt < 7) {
      STAGE_KV_(buf ^ 1, kt + 1);
      asm volatile("s_waitcnt vmcnt(4)" ::: "memory");  // force tile kt, keep kt+1 in flight
    } else {
      asm volatile("s_waitcnt vmcnt(0)" ::: "memory");
    }
    __builtin_amdgcn_s_barrier();

    // ST = K-tile @ Q^T (swapped): ST[tn][tm] reg -> key=krow0+tn*16+quad*4+reg,
    // qrow = qrow0 + tm*16 + l15
    f32x4 ST[4][2];
#pragma unroll
    for (int i = 0; i < 4; i++)
#pragma unroll
      for (int j = 0; j < 2; j++) ST[i][j] = z4;
#pragma unroll
    for (int s = 0; s < 4; s++) {
      f16x8 bfr[4];
#pragma unroll
      for (int tn = 0; tn < 4; tn++) {
        int phys = (s * 4 + quad + l15) & 15;
        bfr[tn] = *(const f16x8*)&Ksb[(tn * 16 + l15) * 128 + phys * 8];
      }
      __builtin_amdgcn_s_setprio(1);
#pragma unroll
      for (int tn = 0; tn < 4; tn++)
#pragma unroll
        for (int tm = 0; tm < 2; tm++)
          ST[tn][tm] = __builtin_amdgcn_mfma_f32_16x16x32_f16(bfr[tn], qf[tm][s], ST[tn][tm], 0, 0, 0);
      __builtin_amdgcn_s_setprio(0);
    }

    // softmax (fixed-max, diag->1) + in-register P->A-frag pack
    f16x8 pa[2][2];   // [tm][ks]
#pragma unroll
    for (int tm = 0; tm < 2; tm++) {
      const int qg = qrow0 + tm * 16 + l15;
      float rs = 0.f;
      unsigned int H[4][2];
#pragma unroll
      for (int tn = 0; tn < 4; tn++) {
        float p[4];
#pragma unroll
        for (int reg = 0; reg < 4; reg++) {
          int kg = krow0 + tn * 16 + quad * 4 + reg;
          float v = (kg == qg) ? 1.f : __expf(ST[tn][tm][reg]);
          p[reg] = v;
          rs += v;
        }
        f16x2 h01 = {(f16)p[0], (f16)p[1]};
        f16x2 h23 = {(f16)p[2], (f16)p[3]};
        H[tn][0] = __builtin_bit_cast(unsigned int, h01);
        H[tn][1] = __builtin_bit_cast(unsigned int, h23);
      }
      rs += __shfl_xor(rs, 16);
      rs += __shfl_xor(rs, 32);
      lrow[tm] += rs;

      // pa[tm][ks] word w holds keys ks*32 + quad*8 + 2w,2w+1
#pragma unroll
      for (int ks = 0; ks < 2; ks++) {
        unsigned int a0 = H[ks * 2][0], a1 = H[ks * 2][1];
        unsigned int b0 = H[ks * 2 + 1][0], b1 = H[ks * 2 + 1][1];
        // in-place 32-lane half swap: a' = {a.lo, b.lo}, b' = {a.hi, b.hi}
        asm volatile("s_nop 1\n\tv_permlane32_swap_b32 %0, %1\n\ts_nop 1"
                     : "+v"(a0), "+v"(b0));
        asm volatile("s_nop 1\n\tv_permlane32_swap_b32 %0, %1\n\ts_nop 1"
                     : "+v"(a1), "+v"(b1));
        unsigned int c0 = (unsigned int)__shfl_xor((int)a0, 16);
        unsigned int c1 = (unsigned int)__shfl_xor((int)a1, 16);
        unsigned int d0 = (unsigned int)__shfl_xor((int)b0, 16);
        unsigned int d1 = (unsigned int)__shfl_xor((int)b1, 16);
        ui4 wv;
        wv[0] = qodd ? d0 : a0;
        wv[1] = qodd ? d1 : a1;
        wv[2] = qodd ? b0 : c0;
        wv[3] = qodd ? b1 : c1;
        pa[tm][ks] = __builtin_bit_cast(f16x8, wv);
      }
    }

    // O += P @ V
#pragma unroll
    for (int ks = 0; ks < 2; ks++) {
      __builtin_amdgcn_s_setprio(1);
#pragma unroll
      for (int tn = 0; tn < 8; tn++) {
        int phys = (ks * 4 + quad + r7) & 7;
        f16x8 vb = *(const f16x8*)&VTsb[(tn * 16 + l15) * 64 + phys * 8];
#pragma unroll
        for (int tm = 0; tm < 2; tm++)
          O[tm][tn] = __builtin_amdgcn_mfma_f32_16x16x32_f16(pa[tm][ks], vb, O[tm][tn], 0, 0, 0);
      }
      __builtin_amdgcn_s_setprio(0);
    }
    __builtin_amdgcn_s_barrier();
  }
#undef STAGE_KV_

  // epilogue: redistribute lrow (l15-layout -> quad*4+reg layout), O/l -> ctx
#pragma unroll
  for (int tm = 0; tm < 2; tm++)
#pragma unroll
    for (int reg = 0; reg < 4; reg++) {
      float lv = __shfl(lrow[tm], quad * 4 + reg);
      float inv = 1.f / lv;
      int row = bb * SEQ + qrow0 + tm * 16 + quad * 4 + reg;
#pragma unroll
      for (int tn = 0; tn < 8; tn++) {
        int col = h * 128 + tn * 16 + l15;
        ctx[(size_t)row * HDIM + col] = (f16)(O[tm][tn][reg] * inv);
      }
    }
}

// ---------------- launch ----------------

extern "C" void kernel_launch(void* const* d_in, const int* in_sizes, int n_in,
                              void* d_out, int out_size, void* d_ws, size_t ws_size,
                              hipStream_t stream) {
  (void)in_sizes; (void)n_in; (void)out_size; (void)ws_size;
  const float* x      = (const float*)d_in[0];
  const float* conv_w = (const float*)d_in[1];
  const float* conv_b = (const float*)d_in[2];
  const float* w1     = (const float*)d_in[3];
  const float* b1     = (const float*)d_in[4];
  const float* w2     = (const float*)d_in[5];
  const float* b2     = (const float*)d_in[6];
  const float* ln_g   = (const float*)d_in[7];
  const float* ln_b   = (const float*)d_in[8];
  const float* wq     = (const float*)d_in[9];
  const float* bq     = (const float*)d_in[10];
  const float* wk     = (const float*)d_in[11];
  const float* bk     = (const float*)d_in[12];
  const float* wv     = (const float*)d_in[13];
  const float* bv     = (const float*)d_in[14];
  const float* wo     = (const float*)d_in[15];
  const float* bo     = (const float*)d_in[16];
  const float* wp     = (const float*)d_in[17];
  const float* bp     = (const float*)d_in[18];
  float* out = (float*)d_out;

  char* ws = (char*)d_ws;
  size_t off = 0;
  auto alloc = [&](size_t bytes) {
    char* p = ws + off;
    off += (bytes + 255) & ~(size_t)255;
    return p;
  };
  float* cs    = (float*)alloc(8);
  f16* w1T     = (f16*)alloc((size_t)1024 * 512 * 2);
  f16* w2T     = (f16*)alloc((size_t)1024 * 1024 * 2);
  f16* qkvT    = (f16*)alloc((size_t)3072 * 1024 * 2);
  f16* wpT     = (f16*)alloc((size_t)1024 * 1024 * 2);
  f16* woh     = (f16*)alloc((size_t)1024 * 1024 * 2);
  f16* woPT    = (f16*)alloc((size_t)1024 * 1024 * 2);
  float* bqkv  = (float*)alloc((size_t)3072 * 4);
  float* bp2   = (float*)alloc((size_t)1024 * 4);
  float* part  = (float*)alloc((size_t)8 * 1024 * 4);
  f16* qkvQK   = (f16*)alloc((size_t)MR * QK_LD * 2);  // 128 MB; front reused as xh
  f16* h1      = (f16*)alloc((size_t)MR * 1024 * 2);   // 64 MB; reused as vT
  f16* x_norm  = (f16*)alloc((size_t)MR * 1024 * 2);   // 64 MB; reused as ctx
  f16* x_regh  = (f16*)alloc((size_t)MR * 1024 * 2);   // 64 MB (residual + LN input)
  f16* xh = qkvQK;    // [32768,512] dead before qkvQK written
  f16* vT = h1;       // h1 dead after w2 gemm
  f16* ctx = x_norm;  // x_norm dead after QKV gemm

  dim3 tb(32, 8);
  conv_reduce<<<1, 256, 0, stream>>>(conv_w, conv_b, cs);
  transpose_cast<<<dim3(32, 16), tb, 0, stream>>>(w1, w1T, 512, 1024);
  transpose_cast5<<<dim3(32, 32, 5), tb, 0, stream>>>(
      w2, wq, wk, wv, wp,
      w2T, qkvT, qkvT + (size_t)1024 * 1024, qkvT + (size_t)2048 * 1024, wpT);
  cast_f16<<<1024, 256, 0, stream>>>(wo, woh);
  concat_bias<<<12, 256, 0, stream>>>(bq, bk, bv, bqkv);
  fuse_bias_p1<<<dim3(4, 8), 256, 0, stream>>>(bo, wp, part);
  fuse_bias_p2<<<4, 256, 0, stream>>>(part, bp, bp2);
  prep_x<<<16384, 256, 0, stream>>>(x, cs, xh);

  // woPT[n][k] = (wo@wp)[k][n]
  gemm_nt<4><<<dim3(64), 512, 0, stream>>>(wpT, woh, nullptr, (void*)woPT, 1024, 1024, nullptr, nullptr);

  gemm_nt<0><<<dim3(256 * 8), 512, 0, stream>>>(xh, w1T, b1, (void*)h1, 1024, 512, nullptr, nullptr);
  gemm_nt<1><<<dim3(256 * 8), 512, 0, stream>>>(h1, w2T, b2, (void*)x_regh, 1024, 1024, nullptr, nullptr);
  ln_kernel<<<32768, 256, 0, stream>>>(x_regh, ln_g, ln_b, x_norm);
  // QKV: q,k -> qkvQK (LD 2048); v -> vT directly
  gemm_nt<6><<<dim3(256 * 24), 512, 0, stream>>>(x_norm, qkvT, bqkv, (void*)qkvQK, 3072, 1024, nullptr, vT);
  attn_kernel<<<1024, 512, 0, stream>>>(qkvQK, vT, ctx);
  // fused wo+wp: out = ctx @ woP + bp2 + x_reg
  gemm_nt<5><<<dim3(256 * 8), 512, 0, stream>>>(ctx, woPT, bp2, (void*)out, 1024, 1024, x_regh, nullptr);
}